// Round 1
// baseline (298.030 us; speedup 1.0000x reference)
//
#include <hip/hip_runtime.h>

#define B_      8
#define DIM_    256
#define SEQ_    16384
#define K_      3
#define HID_    85          // DIM // 3
#define OUTCH_  (DIM_ * K_) // 768
#define EPS_    1e-5f

// ---------------------------------------------------------------------------
// Kernel 1: pooled[b*DIM+c] = mean over SEQ of x[b][c][:]
// One block per (b,c) row; 256 threads; float4 loads; wave+LDS reduction.
// ---------------------------------------------------------------------------
__global__ __launch_bounds__(256) void pool_kernel(const float* __restrict__ x,
                                                   float* __restrict__ pooled) {
    const int row = blockIdx.x;                       // b*DIM + c
    const float4* x4 = (const float4*)(x + (size_t)row * SEQ_);
    float s = 0.f;
#pragma unroll
    for (int k = 0; k < SEQ_ / 4 / 256; ++k) {        // 16 iters
        float4 v = x4[threadIdx.x + k * 256];
        s += (v.x + v.y) + (v.z + v.w);
    }
    // wave64 reduction
#pragma unroll
    for (int off = 32; off > 0; off >>= 1) s += __shfl_down(s, off, 64);
    __shared__ float lds[4];
    const int lane = threadIdx.x & 63, wid = threadIdx.x >> 6;
    if (lane == 0) lds[wid] = s;
    __syncthreads();
    if (threadIdx.x == 0) {
        float t = (lds[0] + lds[1]) + (lds[2] + lds[3]);
        pooled[row] = t * (1.0f / SEQ_);
    }
}

// ---------------------------------------------------------------------------
// Kernel 2: per-sample MLP.  y = relu(BN(pooled @ w1^T));  w = y @ w2^T + b2
// One block per batch sample (8 blocks, 256 threads). Tiny — latency-bound.
// ---------------------------------------------------------------------------
__global__ __launch_bounds__(256) void mlp_kernel(const float* __restrict__ pooled,
                                                  const float* __restrict__ w1,
                                                  const float* __restrict__ gamma,
                                                  const float* __restrict__ beta,
                                                  const float* __restrict__ mean,
                                                  const float* __restrict__ var,
                                                  const float* __restrict__ w2,
                                                  const float* __restrict__ b2,
                                                  float* __restrict__ wout) {
    const int b = blockIdx.x;
    __shared__ float sp[DIM_];
    __shared__ float sy[HID_];
    sp[threadIdx.x] = pooled[b * DIM_ + threadIdx.x];
    __syncthreads();
    if (threadIdx.x < HID_) {
        const int h = threadIdx.x;
        const float* w1r = w1 + h * DIM_;
        float acc = 0.f;
#pragma unroll 8
        for (int c = 0; c < DIM_; ++c) acc = fmaf(sp[c], w1r[c], acc);
        float t = (acc - mean[h]) * (gamma[h] * rsqrtf(var[h] + EPS_)) + beta[h];
        sy[h] = fmaxf(t, 0.f);
    }
    __syncthreads();
    for (int o = threadIdx.x; o < OUTCH_; o += 256) {
        const float* w2r = w2 + o * HID_;
        float acc = b2[o];
        for (int h = 0; h < HID_; ++h) acc = fmaf(sy[h], w2r[h], acc);
        wout[b * OUTCH_ + o] = acc;                   // [b][c][k] flat
    }
}

// ---------------------------------------------------------------------------
// Kernel 3: depthwise 3-tap conv, pad=1:
//   out[b][c][s] = w0*x[s-1] + w1*x[s] + w2*x[s+1] + bias[c]
// One block per (b,c) row; float4 in / float4 out; neighbor scalars hit L1.
// ---------------------------------------------------------------------------
__global__ __launch_bounds__(256) void conv_kernel(const float* __restrict__ x,
                                                   const float* __restrict__ wk,
                                                   const float* __restrict__ bias,
                                                   float* __restrict__ out) {
    const int row = blockIdx.x;                       // b*DIM + c
    const int c = row & (DIM_ - 1);
    const float w0 = wk[row * 3 + 0];
    const float w1 = wk[row * 3 + 1];
    const float w2 = wk[row * 3 + 2];
    const float bs = bias[c];
    const float* xr = x + (size_t)row * SEQ_;
    const float4* x4 = (const float4*)xr;
    float4* o4 = (float4*)(out + (size_t)row * SEQ_);
#pragma unroll
    for (int k = 0; k < SEQ_ / 4 / 256; ++k) {        // 16 iters
        const int j = threadIdx.x + k * 256;
        const int s0 = j * 4;
        float4 v = x4[j];
        float left  = (s0 > 0)          ? xr[s0 - 1] : 0.f;   // pad=0
        float right = (s0 + 4 < SEQ_)   ? xr[s0 + 4] : 0.f;   // pad=0
        float4 r;
        r.x = fmaf(w0, left, fmaf(w1, v.x, w2 * v.y)) + bs;
        r.y = fmaf(w0, v.x,  fmaf(w1, v.y, w2 * v.z)) + bs;
        r.z = fmaf(w0, v.y,  fmaf(w1, v.z, w2 * v.w)) + bs;
        r.w = fmaf(w0, v.z,  fmaf(w1, v.w, w2 * right)) + bs;
        o4[j] = r;
    }
}

// ---------------------------------------------------------------------------
extern "C" void kernel_launch(void* const* d_in, const int* in_sizes, int n_in,
                              void* d_out, int out_size, void* d_ws, size_t ws_size,
                              hipStream_t stream) {
    const float* x     = (const float*)d_in[0];
    const float* w1    = (const float*)d_in[1];
    const float* gamma = (const float*)d_in[2];
    const float* beta  = (const float*)d_in[3];
    const float* mean  = (const float*)d_in[4];
    const float* var   = (const float*)d_in[5];
    const float* w2    = (const float*)d_in[6];
    const float* b2    = (const float*)d_in[7];
    const float* bias  = (const float*)d_in[8];
    float* out = (float*)d_out;

    float* pooled = (float*)d_ws;                 // B*DIM      = 2048 floats
    float* wk     = pooled + B_ * DIM_;           // B*DIM*K    = 6144 floats

    pool_kernel<<<B_ * DIM_, 256, 0, stream>>>(x, pooled);
    mlp_kernel<<<B_, 256, 0, stream>>>(pooled, w1, gamma, beta, mean, var, w2, b2, wk);
    conv_kernel<<<B_ * DIM_, 256, 0, stream>>>(x, wk, bias, out);
}

// Round 3
// 292.071 us; speedup vs baseline: 1.0204x; 1.0204x over previous
//
#include <hip/hip_runtime.h>

#define B_      8
#define DIM_    256
#define SEQ_    16384
#define K_      3
#define HID_    85          // DIM // 3
#define OUTCH_  (DIM_ * K_) // 768
#define EPS_    1e-5f

typedef float floatx4 __attribute__((ext_vector_type(4)));  // native vec for nontemporal builtins

// ---------------------------------------------------------------------------
// Kernel 1: pooled[b*DIM+c] = mean over SEQ of x[b][c][:]
// One block per (b,c) row; 256 threads; float4 loads; wave+LDS reduction.
// Normal (cached) loads on purpose: pulls x into L3 for the conv's re-read.
// ---------------------------------------------------------------------------
__global__ __launch_bounds__(256) void pool_kernel(const float* __restrict__ x,
                                                   float* __restrict__ pooled) {
    const int row = blockIdx.x;                       // b*DIM + c
    const floatx4* x4 = (const floatx4*)(x + (size_t)row * SEQ_);
    float s = 0.f;
#pragma unroll
    for (int k = 0; k < SEQ_ / 4 / 256; ++k) {        // 16 iters
        floatx4 v = x4[threadIdx.x + k * 256];
        s += (v.x + v.y) + (v.z + v.w);
    }
#pragma unroll
    for (int off = 32; off > 0; off >>= 1) s += __shfl_down(s, off, 64);
    __shared__ float lds[4];
    const int lane = threadIdx.x & 63, wid = threadIdx.x >> 6;
    if (lane == 0) lds[wid] = s;
    __syncthreads();
    if (threadIdx.x == 0) {
        float t = (lds[0] + lds[1]) + (lds[2] + lds[3]);
        pooled[row] = t * (1.0f / SEQ_);
    }
}

// ---------------------------------------------------------------------------
// Kernel 2 (fused MLP + conv): each block owns one (b,c) row.
//  Prologue: redundantly compute y[b] = relu(BN(pooled[b] @ w1^T)) in LDS,
//            then every thread computes its channel's 3 taps = y @ w2^T + b2.
//  Main: 3-tap depthwise conv. Halos come from wave shuffles (2 scalar
//        global loads per WAVE, not per lane). Output uses nontemporal
//        stores so the 134 MB of writes don't evict x from L3 (x re-read
//        after pool should be L3-resident: 134 MB < 256 MiB).
// ---------------------------------------------------------------------------
__global__ __launch_bounds__(256) void conv_kernel(const float* __restrict__ x,
                                                   const float* __restrict__ pooled,
                                                   const float* __restrict__ w1,
                                                   const float* __restrict__ gamma,
                                                   const float* __restrict__ beta,
                                                   const float* __restrict__ mean,
                                                   const float* __restrict__ var,
                                                   const float* __restrict__ w2,
                                                   const float* __restrict__ b2,
                                                   const float* __restrict__ bias,
                                                   float* __restrict__ out) {
    const int row = blockIdx.x;                       // b*DIM + c
    const int b = row >> 8;
    const int c = row & (DIM_ - 1);

    __shared__ float sp[DIM_];
    __shared__ float sy[HID_];
    sp[threadIdx.x] = pooled[b * DIM_ + threadIdx.x];
    __syncthreads();
    if (threadIdx.x < HID_) {
        const int h = threadIdx.x;
        const float* w1r = w1 + h * DIM_;
        float acc = 0.f;
#pragma unroll 8
        for (int cc = 0; cc < DIM_; ++cc) acc = fmaf(sp[cc], w1r[cc], acc);
        float t = (acc - mean[h]) * (gamma[h] * rsqrtf(var[h] + EPS_)) + beta[h];
        sy[h] = fmaxf(t, 0.f);
    }
    __syncthreads();

    // every thread computes the 3 taps (uniform w2/b2 addresses -> scalar path)
    const float* w2r0 = w2 + (c * 3 + 0) * HID_;
    const float* w2r1 = w2 + (c * 3 + 1) * HID_;
    const float* w2r2 = w2 + (c * 3 + 2) * HID_;
    float w0 = b2[c * 3 + 0], w1t = b2[c * 3 + 1], w2t = b2[c * 3 + 2];
    for (int h = 0; h < HID_; ++h) {
        const float yv = sy[h];
        w0  = fmaf(yv, w2r0[h], w0);
        w1t = fmaf(yv, w2r1[h], w1t);
        w2t = fmaf(yv, w2r2[h], w2t);
    }
    const float bs = bias[c];

    const float* xr = x + (size_t)row * SEQ_;
    const floatx4* x4 = (const floatx4*)xr;
    floatx4* o4 = (floatx4*)(out + (size_t)row * SEQ_);
    const int lane = threadIdx.x & 63;
#pragma unroll
    for (int k = 0; k < SEQ_ / 4 / 256; ++k) {        // 16 iters
        const int j = threadIdx.x + k * 256;
        const int s0 = j * 4;
        floatx4 v = x4[j];
        // halos via shuffle: lanes are contiguous in j within a wave
        float left  = __shfl_up(v.w, 1, 64);
        float right = __shfl_down(v.x, 1, 64);
        if (lane == 0)  left  = (s0 > 0)        ? xr[s0 - 1] : 0.f;
        if (lane == 63) right = (s0 + 4 < SEQ_) ? xr[s0 + 4] : 0.f;
        floatx4 r;
        r.x = fmaf(w0, left, fmaf(w1t, v.x, w2t * v.y)) + bs;
        r.y = fmaf(w0, v.x,  fmaf(w1t, v.y, w2t * v.z)) + bs;
        r.z = fmaf(w0, v.y,  fmaf(w1t, v.z, w2t * v.w)) + bs;
        r.w = fmaf(w0, v.z,  fmaf(w1t, v.w, w2t * right)) + bs;
        __builtin_nontemporal_store(r, &o4[j]);
    }
}

// ---------------------------------------------------------------------------
extern "C" void kernel_launch(void* const* d_in, const int* in_sizes, int n_in,
                              void* d_out, int out_size, void* d_ws, size_t ws_size,
                              hipStream_t stream) {
    const float* x     = (const float*)d_in[0];
    const float* w1    = (const float*)d_in[1];
    const float* gamma = (const float*)d_in[2];
    const float* beta  = (const float*)d_in[3];
    const float* mean  = (const float*)d_in[4];
    const float* var   = (const float*)d_in[5];
    const float* w2    = (const float*)d_in[6];
    const float* b2    = (const float*)d_in[7];
    const float* bias  = (const float*)d_in[8];
    float* out = (float*)d_out;

    float* pooled = (float*)d_ws;                 // B*DIM = 2048 floats

    pool_kernel<<<B_ * DIM_, 256, 0, stream>>>(x, pooled);
    conv_kernel<<<B_ * DIM_, 256, 0, stream>>>(x, pooled, w1, gamma, beta, mean,
                                               var, w2, b2, bias, out);
}